// Round 1
// baseline (681.389 us; speedup 1.0000x reference)
//
#include <hip/hip_runtime.h>
#include <hip/hip_bf16.h>

// DynamicLoRALinear: out = x @ W^T + b + 2.0 * ((x @ A[slot]) @ Bm[slot])
// fp32 I/O; compute in bf16 MFMA (absmax 0.031 vs threshold 0.1425).
// R6: GEMM rebuilt as 256^2-tile / BK=64 / 8-wave / 4-phase schedule (T3+T4+T5):
//     - 128 KiB LDS double buffer, zero-conflict XOR-(row&7) swizzle kept from R4
//     - prefetch issued in phases 1-2, boundary vmcnt(0) waits on well-aged loads
//     - setprio(1) around each 16-MFMA cluster (phase-split => T5 applies, m218b)
//     lora_hx / cvt unchanged to isolate the GEMM delta.

typedef __bf16 bf16_t;
typedef __bf16 bf16x8 __attribute__((ext_vector_type(8)));
typedef __bf16 bf16x4 __attribute__((ext_vector_type(4)));
typedef float f32x4 __attribute__((ext_vector_type(4)));

#define M_DIM 8192
#define K_DIM 4096
#define N_DIM 4096
#define SCALE_F 2.0f
#define NT (K_DIM / 64)   // 64 K-tiles of 64

__device__ __forceinline__ void gload_lds16(const void* g, void* l) {
    __builtin_amdgcn_global_load_lds(
        (const __attribute__((address_space(1))) void*)g,
        (__attribute__((address_space(3))) void*)l, 16, 0, 0);
}

// ---------------- fp32 -> bf16 bulk convert (for W) ----------------
__global__ __launch_bounds__(256) void cvt_kernel(const float* __restrict__ src,
                                                  bf16_t* __restrict__ dst, int n4) {
    int i = blockIdx.x * 256 + threadIdx.x;
    const int stride = gridDim.x * 256;
    for (; i < n4; i += stride) {
        f32x4 v = ((const f32x4*)src)[i];
        bf16x4 o = {(bf16_t)v[0], (bf16_t)v[1], (bf16_t)v[2], (bf16_t)v[3]};
        ((bf16x4*)dst)[i] = o;
    }
}

// ------- kernel 1: fused X->bf16 emit + h = 2.0*(x@A[slot]) via MFMA -------
__global__ __launch_bounds__(256) void lora_hx_kernel(
    const float* __restrict__ X,
    const float* __restrict__ lora_As,
    const int* __restrict__ mapping,
    float* __restrict__ h_ws,
    bf16_t* __restrict__ Xb)            // null in fallback path
{
    __shared__ bf16_t Xt[32 * 16 * 8];  // 8 KB, swizzled chunks of 8 bf16
    __shared__ bf16_t At[16 * 136];     // 4.25 KB, [r][k] padded
    __shared__ float hred[4 * 2 * 16 * 16];  // 8 KB

    const int tid  = threadIdx.x;
    const int wave = tid >> 6;
    const int lane = tid & 63;
    const int bm0  = blockIdx.x * 32;
    const int slot = mapping[bm0 >> 10];
    const float* __restrict__ A = lora_As + (size_t)slot * (K_DIM * 16);

    const int srow = tid >> 3;          // 0..31 staging row
    const int sc2  = tid & 7;           // chunk-pair 0..7
    const int r16  = lane & 15;
    const int kq   = lane >> 4;

    f32x4 acc[2];
    acc[0] = (f32x4){0.f, 0.f, 0.f, 0.f};
    acc[1] = (f32x4){0.f, 0.f, 0.f, 0.f};

    for (int k0 = 0; k0 < K_DIM; k0 += 128) {
        const float* xp = X + (size_t)(bm0 + srow) * K_DIM + k0 + sc2 * 16;
        f32x4 v0 = *(const f32x4*)(xp);
        f32x4 v1 = *(const f32x4*)(xp + 4);
        f32x4 v2 = *(const f32x4*)(xp + 8);
        f32x4 v3 = *(const f32x4*)(xp + 12);
        bf16x8 c0 = {(bf16_t)v0[0], (bf16_t)v0[1], (bf16_t)v0[2], (bf16_t)v0[3],
                     (bf16_t)v1[0], (bf16_t)v1[1], (bf16_t)v1[2], (bf16_t)v1[3]};
        bf16x8 c1 = {(bf16_t)v2[0], (bf16_t)v2[1], (bf16_t)v2[2], (bf16_t)v2[3],
                     (bf16_t)v3[0], (bf16_t)v3[1], (bf16_t)v3[2], (bf16_t)v3[3]};
        if (Xb) {
            bf16x8* xbp = (bf16x8*)(Xb + (size_t)(bm0 + srow) * K_DIM + k0 + sc2 * 16);
            xbp[0] = c0;
            xbp[1] = c1;
        }
        const int k8a = sc2 * 2, k8b = sc2 * 2 + 1;
        *(bf16x8*)(Xt + (srow * 16 + (k8a ^ (srow & 15))) * 8) = c0;
        *(bf16x8*)(Xt + (srow * 16 + (k8b ^ (srow & 15))) * 8) = c1;

        {
            const int kk = tid >> 1, half = tid & 1;
            const float* ap = A + (size_t)(k0 + kk) * 16 + half * 8;
            f32x4 a0 = *(const f32x4*)ap;
            f32x4 a1 = *(const f32x4*)(ap + 4);
#pragma unroll
            for (int rr = 0; rr < 4; ++rr) {
                At[(half * 8 + rr) * 136 + kk]     = (bf16_t)a0[rr];
                At[(half * 8 + 4 + rr) * 136 + kk] = (bf16_t)a1[rr];
            }
        }
        __syncthreads();

#pragma unroll
        for (int i = 0; i < 2; ++i) {
            const int row_l = i * 16 + r16;
            const int c = wave * 4 + kq;
            bf16x8 af  = *(const bf16x8*)(Xt + (row_l * 16 + (c ^ (row_l & 15))) * 8);
            bf16x8 bfr = *(const bf16x8*)(At + r16 * 136 + wave * 32 + kq * 8);
            acc[i] = __builtin_amdgcn_mfma_f32_16x16x32_bf16(af, bfr, acc[i], 0, 0, 0);
        }
        __syncthreads();
    }

#pragma unroll
    for (int i = 0; i < 2; ++i)
#pragma unroll
        for (int e = 0; e < 4; ++e)
            hred[wave * 512 + i * 256 + (kq * 4 + e) * 16 + r16] = acc[i][e];
    __syncthreads();
#pragma unroll
    for (int q = 0; q < 2; ++q) {
        const int entry = tid * 2 + q;
        const int row_l = entry >> 4, col = entry & 15;
        const int i = row_l >> 4, rr = row_l & 15;
        const int off = i * 256 + rr * 16 + col;
        float s = hred[off] + hred[512 + off] + hred[1024 + off] + hred[1536 + off];
        h_ws[(size_t)(bm0 + row_l) * 16 + col] = s * SCALE_F;
    }
}

// ---- epilogue for the 64x64-per-wave fallback kernel (unchanged) ----
__device__ __forceinline__ void epilogue(
    f32x4 (&acc)[4][4], const float* __restrict__ bias,
    const float* __restrict__ lora_Bs, const int* __restrict__ mapping,
    const float* __restrict__ h_ws, float* __restrict__ out,
    int bm0, int bn0, int wm0, int wn0, int r16, int kq)
{
    const int slot = mapping[bm0 >> 10];
    const bool hasK = (kq < 2);
    const int kq2 = hasK ? kq : 0;

    bf16x8 hfrag[4], bmf[4];
#pragma unroll
    for (int i = 0; i < 4; ++i) {
        const float* hp = h_ws + (size_t)(bm0 + wm0 + i * 16 + r16) * 16 + kq2 * 8;
        f32x4 h0 = *(const f32x4*)hp;
        f32x4 h1 = *(const f32x4*)(hp + 4);
#pragma unroll
        for (int jj = 0; jj < 4; ++jj) {
            hfrag[i][jj]     = hasK ? (bf16_t)h0[jj] : (bf16_t)0.f;
            hfrag[i][jj + 4] = hasK ? (bf16_t)h1[jj] : (bf16_t)0.f;
        }
    }
#pragma unroll
    for (int j = 0; j < 4; ++j) {
        const int o = bn0 + wn0 + j * 16 + r16;
#pragma unroll
        for (int jj = 0; jj < 8; ++jj) {
            const int r = kq2 * 8 + jj;
            const float v = lora_Bs[((size_t)slot * 16 + r) * N_DIM + o];
            bmf[j][jj] = hasK ? (bf16_t)v : (bf16_t)0.f;
        }
    }
#pragma unroll
    for (int i = 0; i < 4; ++i)
#pragma unroll
        for (int j = 0; j < 4; ++j)
            acc[i][j] = __builtin_amdgcn_mfma_f32_16x16x32_bf16(hfrag[i], bmf[j], acc[i][j], 0, 0, 0);

#pragma unroll
    for (int j = 0; j < 4; ++j) {
        const int o = bn0 + wn0 + j * 16 + r16;
        const float bv = bias[o];
#pragma unroll
        for (int i = 0; i < 4; ++i) {
#pragma unroll
            for (int e = 0; e < 4; ++e) {
                const int m = bm0 + wm0 + i * 16 + kq * 4 + e;
                out[(size_t)m * N_DIM + o] = acc[i][j][e] + bv;
            }
        }
    }
}

// ---- staging for the 256^2 kernel: 32KB tile, 4 x gload_lds16 per thread ----
// Dest is linear (HW requirement); the XOR-(row&7) chunk swizzle is applied to
// the GLOBAL source address (both-sides-or-neither). 128B-contiguous per row.
__device__ __forceinline__ void stage256(const bf16_t* __restrict__ G, int grow0, int k0,
                                         bf16_t* lds, int wave, int lane) {
#pragma unroll
    for (int p = 0; p < 4; ++p) {
        const int base = p * 512 + wave * 64;      // wave-uniform slot base
        const int s    = base + lane;
        const int row  = s >> 3;
        const int c    = (s & 7) ^ (row & 7);
        gload_lds16(G + (size_t)(grow0 + row) * K_DIM + k0 + c * 8,
                    lds + (size_t)base * 8);
    }
}

// ---------------- main GEMM: 256x256 tile, BK=64, 8 waves, 4 phases ----------------
__global__ __launch_bounds__(512, 2) void gemm_lora_256(
    const bf16_t* __restrict__ Xb, const bf16_t* __restrict__ Wb,
    const float* __restrict__ bias, const float* __restrict__ lora_Bs,
    const int* __restrict__ mapping, const float* __restrict__ h_ws,
    float* __restrict__ out)
{
    __shared__ bf16_t As[2][256 * 64];   // 2 x 32 KB
    __shared__ bf16_t Bs[2][256 * 64];   // 2 x 32 KB   (128 KiB total)

    const int tid  = threadIdx.x;
    const int wave = tid >> 6;
    const int lane = tid & 63;
    const int bid  = blockIdx.x;
    // XCD-aware bijective swizzle: nwg = 512, divisible by 8
    const int wgid = (bid & 7) * 64 + (bid >> 3);
    const int m_t  = wgid >> 4;          // 0..31
    const int n_t  = wgid & 15;          // 0..15
    const int bm0  = m_t * 256;
    const int bn0  = n_t * 256;
    const int wr   = wave >> 2;          // 0..1  (m half: 128 rows)
    const int wc   = wave & 3;           // 0..3  (n quarter: 64 cols)
    const int r16  = lane & 15;
    const int kq   = lane >> 4;

    f32x4 acc[8][4];
#pragma unroll
    for (int i = 0; i < 8; ++i)
#pragma unroll
        for (int j = 0; j < 4; ++j) acc[i][j] = (f32x4){0.f, 0.f, 0.f, 0.f};

    // prologue: stage tile 0 into buffer 0, full drain once
    stage256(Xb, bm0, 0, As[0], wave, lane);
    stage256(Wb, bn0, 0, Bs[0], wave, lane);
    asm volatile("s_waitcnt vmcnt(0)" ::: "memory");
    __builtin_amdgcn_s_barrier();

#pragma unroll 2
    for (int t = 0; t < NT; ++t) {
        const int b = t & 1;
        const bf16_t* Ab = As[b];
        const bf16_t* Bb = Bs[b];
        bf16_t* An = As[b ^ 1];
        bf16_t* Bn = Bs[b ^ 1];
        const bool pre = (t + 1 < NT);
        const int k0n  = (t + 1) * 64;

        bf16x8 af[4], bfr[4];

        // ---------- phase 1: kh0, m-frags 0-3; stage next A ----------
#pragma unroll
        for (int i = 0; i < 4; ++i) {
            const int ra = wr * 128 + i * 16 + r16;
            af[i] = *(const bf16x8*)(Ab + ((size_t)ra * 8 + (kq ^ (ra & 7))) * 8);
        }
#pragma unroll
        for (int j = 0; j < 4; ++j) {
            const int rb = wc * 64 + j * 16 + r16;
            bfr[j] = *(const bf16x8*)(Bb + ((size_t)rb * 8 + (kq ^ (rb & 7))) * 8);
        }
        if (pre) stage256(Xb, bm0, k0n, An, wave, lane);
        __builtin_amdgcn_s_barrier();
        __builtin_amdgcn_s_setprio(1);
#pragma unroll
        for (int i = 0; i < 4; ++i)
#pragma unroll
            for (int j = 0; j < 4; ++j)
                acc[i][j] = __builtin_amdgcn_mfma_f32_16x16x32_bf16(af[i], bfr[j], acc[i][j], 0, 0, 0);
        __builtin_amdgcn_s_setprio(0);
        __builtin_amdgcn_s_barrier();

        // ---------- phase 2: kh0, m-frags 4-7; stage next B ----------
#pragma unroll
        for (int i = 0; i < 4; ++i) {
            const int ra = wr * 128 + 64 + i * 16 + r16;
            af[i] = *(const bf16x8*)(Ab + ((size_t)ra * 8 + (kq ^ (ra & 7))) * 8);
        }
        if (pre) stage256(Wb, bn0, k0n, Bn, wave, lane);
        __builtin_amdgcn_s_barrier();
        __builtin_amdgcn_s_setprio(1);
#pragma unroll
        for (int i = 0; i < 4; ++i)
#pragma unroll
            for (int j = 0; j < 4; ++j)
                acc[4 + i][j] = __builtin_amdgcn_mfma_f32_16x16x32_bf16(af[i], bfr[j], acc[4 + i][j], 0, 0, 0);
        __builtin_amdgcn_s_setprio(0);
        __builtin_amdgcn_s_barrier();

        // ---------- phase 3: kh1, m-frags 0-3 ----------
#pragma unroll
        for (int i = 0; i < 4; ++i) {
            const int ra = wr * 128 + i * 16 + r16;
            af[i] = *(const bf16x8*)(Ab + ((size_t)ra * 8 + ((4 + kq) ^ (ra & 7))) * 8);
        }
#pragma unroll
        for (int j = 0; j < 4; ++j) {
            const int rb = wc * 64 + j * 16 + r16;
            bfr[j] = *(const bf16x8*)(Bb + ((size_t)rb * 8 + ((4 + kq) ^ (rb & 7))) * 8);
        }
        __builtin_amdgcn_s_barrier();
        __builtin_amdgcn_s_setprio(1);
#pragma unroll
        for (int i = 0; i < 4; ++i)
#pragma unroll
            for (int j = 0; j < 4; ++j)
                acc[i][j] = __builtin_amdgcn_mfma_f32_16x16x32_bf16(af[i], bfr[j], acc[i][j], 0, 0, 0);
        __builtin_amdgcn_s_setprio(0);
        __builtin_amdgcn_s_barrier();

        // ---------- phase 4: kh1, m-frags 4-7; boundary wait ----------
#pragma unroll
        for (int i = 0; i < 4; ++i) {
            const int ra = wr * 128 + 64 + i * 16 + r16;
            af[i] = *(const bf16x8*)(Ab + ((size_t)ra * 8 + ((4 + kq) ^ (ra & 7))) * 8);
        }
        __builtin_amdgcn_s_barrier();
        __builtin_amdgcn_s_setprio(1);
#pragma unroll
        for (int i = 0; i < 4; ++i)
#pragma unroll
            for (int j = 0; j < 4; ++j)
                acc[4 + i][j] = __builtin_amdgcn_mfma_f32_16x16x32_bf16(af[i], bfr[j], acc[4 + i][j], 0, 0, 0);
        __builtin_amdgcn_s_setprio(0);
        if (pre) {
            // loads were issued in phases 1-2 => aged ~2.5 phases of MFMA; near-free
            asm volatile("s_waitcnt vmcnt(0)" ::: "memory");
        }
        __builtin_amdgcn_s_barrier();
    }

    // ---------------- fused LoRA + bias epilogue (8x4 fragments) ----------------
    const int slot = mapping[bm0 >> 10];
    const bool hasK = (kq < 2);
    const int kq2 = hasK ? kq : 0;
    const int wm0 = wr * 128, wn0 = wc * 64;

    bf16x8 hfrag[8], bmf[4];
#pragma unroll
    for (int i = 0; i < 8; ++i) {
        const float* hp = h_ws + (size_t)(bm0 + wm0 + i * 16 + r16) * 16 + kq2 * 8;
        f32x4 h0 = *(const f32x4*)hp;
        f32x4 h1 = *(const f32x4*)(hp + 4);
#pragma unroll
        for (int jj = 0; jj < 4; ++jj) {
            hfrag[i][jj]     = hasK ? (bf16_t)h0[jj] : (bf16_t)0.f;
            hfrag[i][jj + 4] = hasK ? (bf16_t)h1[jj] : (bf16_t)0.f;
        }
    }
#pragma unroll
    for (int j = 0; j < 4; ++j) {
        const int o = bn0 + wn0 + j * 16 + r16;
#pragma unroll
        for (int jj = 0; jj < 8; ++jj) {
            const int r = kq2 * 8 + jj;
            const float v = lora_Bs[((size_t)slot * 16 + r) * N_DIM + o];
            bmf[j][jj] = hasK ? (bf16_t)v : (bf16_t)0.f;
        }
    }
#pragma unroll
    for (int i = 0; i < 8; ++i)
#pragma unroll
        for (int j = 0; j < 4; ++j)
            acc[i][j] = __builtin_amdgcn_mfma_f32_16x16x32_bf16(hfrag[i], bmf[j], acc[i][j], 0, 0, 0);

#pragma unroll
    for (int j = 0; j < 4; ++j) {
        const int o = bn0 + wn0 + j * 16 + r16;
        const float bv = bias[o];
#pragma unroll
        for (int i = 0; i < 8; ++i) {
#pragma unroll
            for (int e = 0; e < 4; ++e) {
                const int m = bm0 + wm0 + i * 16 + kq * 4 + e;
                out[(size_t)m * N_DIM + o] = acc[i][j][e] + bv;
            }
        }
    }
}

// ---------------- fallback: fp32 staging via global_load_lds, BK=32 ----------------
__global__ __launch_bounds__(256) void gemm_lora_f32s(
    const float* __restrict__ Xf, const float* __restrict__ Wf,
    const float* __restrict__ bias, const float* __restrict__ lora_Bs,
    const int* __restrict__ mapping, const float* __restrict__ h_ws,
    float* __restrict__ out)
{
    __shared__ float Asf[128 * 32];
    __shared__ float Bsf[128 * 32];

    const int tid  = threadIdx.x;
    const int wave = tid >> 6;
    const int lane = tid & 63;
    const int bid  = blockIdx.x;
    const int n_t  = (bid & 7) + ((bid >> 9) << 3);
    const int m_t  = (bid >> 3) & 63;
    const int bm0 = m_t * 128;
    const int bn0 = n_t * 128;
    const int wm0 = (wave >> 1) * 64;
    const int wn0 = (wave & 1) * 64;
    const int r16 = lane & 15;
    const int kq  = lane >> 4;

    f32x4 acc[4][4];
#pragma unroll
    for (int i = 0; i < 4; ++i)
#pragma unroll
        for (int j = 0; j < 4; ++j) acc[i][j] = (f32x4){0.f, 0.f, 0.f, 0.f};

    for (int k0 = 0; k0 < K_DIM; k0 += 32) {
#pragma unroll
        for (int p = 0; p < 4; ++p) {
            const int idx0 = (p * 4 + wave) * 64;
            const int idx  = idx0 + lane;
            const int k4   = idx >> 7;
            const int row  = idx & 127;
            gload_lds16(Xf + (size_t)(bm0 + row) * K_DIM + (k0 + k4 * 4),
                        Asf + (size_t)idx0 * 4);
            gload_lds16(Wf + (size_t)(bn0 + row) * K_DIM + (k0 + k4 * 4),
                        Bsf + (size_t)idx0 * 4);
        }
        __syncthreads();

        bf16x8 af[4], bfr[4];
#pragma unroll
        for (int i = 0; i < 4; ++i) {
            const int ra = wm0 + i * 16 + r16;
            const int rb = wn0 + i * 16 + r16;
            f32x4 a0 = *(const f32x4*)(Asf + ((size_t)(kq * 2) * 128 + ra) * 4);
            f32x4 a1 = *(const f32x4*)(Asf + ((size_t)(kq * 2 + 1) * 128 + ra) * 4);
            f32x4 b0 = *(const f32x4*)(Bsf + ((size_t)(kq * 2) * 128 + rb) * 4);
            f32x4 b1 = *(const f32x4*)(Bsf + ((size_t)(kq * 2 + 1) * 128 + rb) * 4);
            af[i]  = (bf16x8){(bf16_t)a0[0], (bf16_t)a0[1], (bf16_t)a0[2], (bf16_t)a0[3],
                              (bf16_t)a1[0], (bf16_t)a1[1], (bf16_t)a1[2], (bf16_t)a1[3]};
            bfr[i] = (bf16x8){(bf16_t)b0[0], (bf16_t)b0[1], (bf16_t)b0[2], (bf16_t)b0[3],
                              (bf16_t)b1[0], (bf16_t)b1[1], (bf16_t)b1[2], (bf16_t)b1[3]};
        }
#pragma unroll
        for (int i = 0; i < 4; ++i)
#pragma unroll
            for (int j = 0; j < 4; ++j)
                acc[i][j] = __builtin_amdgcn_mfma_f32_16x16x32_bf16(af[i], bfr[j], acc[i][j], 0, 0, 0);
        __syncthreads();
    }

    epilogue(acc, bias, lora_Bs, mapping, h_ws, out, bm0, bn0, wm0, wn0, r16, kq);
}

extern "C" void kernel_launch(void* const* d_in, const int* in_sizes, int n_in,
                              void* d_out, int out_size, void* d_ws, size_t ws_size,
                              hipStream_t stream) {
    const float* x        = (const float*)d_in[0];
    const int*   mapping  = (const int*)d_in[1];
    const float* W        = (const float*)d_in[2];
    const float* b        = (const float*)d_in[3];
    const float* lora_As  = (const float*)d_in[4];
    const float* lora_Bs  = (const float*)d_in[5];
    float* out = (float*)d_out;

    const size_t xb_bytes = (size_t)M_DIM * K_DIM * 2;   // 64 MB
    const size_t wb_bytes = (size_t)N_DIM * K_DIM * 2;   // 32 MB
    const size_t h_bytes  = (size_t)M_DIM * 16 * 4;      // 512 KB
    const bool direct = ws_size >= xb_bytes + wb_bytes + h_bytes;

    bf16_t* Xb = (bf16_t*)d_ws;
    bf16_t* Wb = (bf16_t*)((char*)d_ws + xb_bytes);
    float*  h_ws = direct ? (float*)((char*)d_ws + xb_bytes + wb_bytes)
                          : (float*)d_ws;

    lora_hx_kernel<<<dim3(M_DIM / 32), 256, 0, stream>>>(
        x, lora_As, mapping, h_ws, direct ? Xb : nullptr);

    if (direct) {
        cvt_kernel<<<dim3(2048), 256, 0, stream>>>(W, Wb, N_DIM * K_DIM / 4);
        gemm_lora_256<<<dim3((M_DIM / 256) * (N_DIM / 256)), 512, 0, stream>>>(
            Xb, Wb, b, lora_Bs, mapping, h_ws, out);
    } else {
        gemm_lora_f32s<<<dim3(2048), 256, 0, stream>>>(
            x, W, b, lora_Bs, mapping, h_ws, out);
    }
}